// Round 1
// baseline (1835.374 us; speedup 1.0000x reference)
//
#include <hip/hip_runtime.h>

#define Bq 16
#define Nq 2048
#define Sq 4096
#define Dq 128
#define NNZq 1048576

// 32 contiguous lanes cooperate on one nonzero:
//   lane t loads float4 #t of the 128-float emb row (512 B coalesced),
//   scales by mask_values, and scatter-adds into the output row with
//   4 hardware fp32 atomics (global_atomic_add_f32 via unsafeAtomicAdd).
__global__ __launch_bounds__(256) void simple_node_embedder_scatter(
    const int* __restrict__ subnode_ids,    // [B,S]
    const int* __restrict__ mask_batch,     // [NNZ]
    const int* __restrict__ mask_node,      // [NNZ]
    const int* __restrict__ mask_subnode,   // [NNZ]
    const float* __restrict__ mask_values,  // [NNZ]
    const float* __restrict__ emb,          // [VOCAB,D]
    float* __restrict__ out)                // [B,N,D] (pre-zeroed)
{
    int gid  = blockIdx.x * blockDim.x + threadIdx.x;
    int nz   = gid >> 5;   // one nonzero per 32-lane group
    int lane = gid & 31;
    if (nz >= NNZq) return;

    int   b = mask_batch[nz];
    int   n = mask_node[nz];
    int   s = mask_subnode[nz];
    float v = mask_values[nz];

    int token = subnode_ids[b * Sq + s];

    const float4* src = reinterpret_cast<const float4*>(emb + (size_t)token * Dq) + lane;
    float4 e = *src;

    float* dst = out + (size_t)(b * Nq + n) * Dq + lane * 4;
    unsafeAtomicAdd(dst + 0, e.x * v);
    unsafeAtomicAdd(dst + 1, e.y * v);
    unsafeAtomicAdd(dst + 2, e.z * v);
    unsafeAtomicAdd(dst + 3, e.w * v);
}

extern "C" void kernel_launch(void* const* d_in, const int* in_sizes, int n_in,
                              void* d_out, int out_size, void* d_ws, size_t ws_size,
                              hipStream_t stream) {
    const int*   subnode_ids  = (const int*)d_in[0];
    const int*   mask_batch   = (const int*)d_in[1];
    const int*   mask_node    = (const int*)d_in[2];
    const int*   mask_subnode = (const int*)d_in[3];
    const float* mask_values  = (const float*)d_in[4];
    const float* emb_table    = (const float*)d_in[5];
    float*       out          = (float*)d_out;

    // Harness poisons d_out with 0xAA before every timed launch; we need zeros.
    hipMemsetAsync(out, 0, (size_t)out_size * sizeof(float), stream);

    // 32 threads per nonzero; 256-thread blocks -> 8 nonzeros per block.
    const int threads = 256;
    const int blocks  = (NNZq * 32) / threads;  // 131072 blocks
    simple_node_embedder_scatter<<<blocks, threads, 0, stream>>>(
        subnode_ids, mask_batch, mask_node, mask_subnode, mask_values,
        emb_table, out);
}

// Round 2
// 303.437 us; speedup vs baseline: 6.0486x; 6.0486x over previous
//
#include <hip/hip_runtime.h>

#define Bq 16
#define Nq 2048
#define Sq 4096
#define Dq 128
#define NNZq 1048576
#define ROWS (Bq * Nq)  // 32768

// ---------- Phase 1: histogram of destination rows ----------
__global__ __launch_bounds__(256) void count_kernel(
    const int* __restrict__ mb, const int* __restrict__ mn, int* __restrict__ cnt)
{
    int i = blockIdx.x * 256 + threadIdx.x;  // grid sized exactly to NNZ
    int row = mb[i] * Nq + mn[i];
    atomicAdd(&cnt[row], 1);
}

// ---------- Phase 2: exclusive prefix scan of 32768 counts (one block) ----------
__global__ __launch_bounds__(1024) void scan_kernel(
    const int* __restrict__ cnt, int* __restrict__ off, int* __restrict__ cur)
{
    __shared__ int tot[1024];
    int t = threadIdx.x;
    int base = t * 32;
    int local[32];
    int s = 0;
    #pragma unroll
    for (int i = 0; i < 32; i++) { local[i] = s; s += cnt[base + i]; }
    tot[t] = s;
    __syncthreads();
    // Hillis-Steele inclusive scan over the 1024 per-thread totals
    for (int d = 1; d < 1024; d <<= 1) {
        int v = (t >= d) ? tot[t - d] : 0;
        __syncthreads();
        tot[t] += v;
        __syncthreads();
    }
    int blockBase = (t == 0) ? 0 : tot[t - 1];
    #pragma unroll
    for (int i = 0; i < 32; i++) {
        int o = blockBase + local[i];
        off[base + i] = o;
        cur[base + i] = o;
    }
}

// ---------- Phase 3: scatter nz indices into CSR buckets ----------
__global__ __launch_bounds__(256) void scatter_kernel(
    const int* __restrict__ mb, const int* __restrict__ mn,
    int* __restrict__ cur, int* __restrict__ bucket)
{
    int i = blockIdx.x * 256 + threadIdx.x;
    int row = mb[i] * Nq + mn[i];
    int pos = atomicAdd(&cur[row], 1);
    bucket[pos] = i;
}

// ---------- Phase 4: per-row gather + register accumulate + single store ----------
// 32 contiguous lanes own one output row; lane t owns float4 column t (512 B row).
__global__ __launch_bounds__(256) void pool_kernel(
    const int* __restrict__ subnode_ids,    // [B,S]
    const int* __restrict__ mask_subnode,   // [NNZ]
    const float* __restrict__ mask_values,  // [NNZ]
    const float* __restrict__ emb,          // [VOCAB,D]
    const int* __restrict__ off,            // [ROWS]
    const int* __restrict__ cnt,            // [ROWS]
    const int* __restrict__ bucket,         // [NNZ]
    float* __restrict__ out)                // [ROWS,D]
{
    int gid  = blockIdx.x * 256 + threadIdx.x;
    int row  = gid >> 5;   // one row per 32-lane group; grid sized to ROWS*32
    int lane = gid & 31;
    int b     = row >> 11;        // row / Nq
    int start = off[row];
    int n     = cnt[row];

    float4 acc = {0.f, 0.f, 0.f, 0.f};
    for (int j0 = 0; j0 < n; j0 += 32) {
        // Cooperative metadata prefetch: lane j resolves entry j0+j's chain.
        int   myToken = 0;
        float myV     = 0.f;
        int j = j0 + lane;
        if (j < n) {
            int nz  = bucket[start + j];
            int s   = mask_subnode[nz];
            myV     = mask_values[nz];
            myToken = subnode_ids[b * Sq + s];
        }
        int lim = min(32, n - j0);
        for (int k = 0; k < lim; k++) {
            int   tok = __shfl(myToken, k, 32);
            float v   = __shfl(myV, k, 32);
            float4 e = reinterpret_cast<const float4*>(emb + (size_t)tok * Dq)[lane];
            acc.x += e.x * v;
            acc.y += e.y * v;
            acc.z += e.z * v;
            acc.w += e.w * v;
        }
    }
    reinterpret_cast<float4*>(out + (size_t)row * Dq)[lane] = acc;
}

extern "C" void kernel_launch(void* const* d_in, const int* in_sizes, int n_in,
                              void* d_out, int out_size, void* d_ws, size_t ws_size,
                              hipStream_t stream) {
    const int*   subnode_ids  = (const int*)d_in[0];
    const int*   mask_batch   = (const int*)d_in[1];
    const int*   mask_node    = (const int*)d_in[2];
    const int*   mask_subnode = (const int*)d_in[3];
    const float* mask_values  = (const float*)d_in[4];
    const float* emb_table    = (const float*)d_in[5];
    float*       out          = (float*)d_out;

    // Workspace layout (ints): cnt[ROWS] | off[ROWS] | cur[ROWS] | bucket[NNZ]
    int* cnt    = (int*)d_ws;
    int* off    = cnt + ROWS;
    int* cur    = off + ROWS;
    int* bucket = cur + ROWS;

    // Harness poisons d_ws with 0xAA — zero the histogram only.
    hipMemsetAsync(cnt, 0, ROWS * sizeof(int), stream);

    count_kernel<<<NNZq / 256, 256, 0, stream>>>(mask_batch, mask_node, cnt);
    scan_kernel<<<1, 1024, 0, stream>>>(cnt, off, cur);
    scatter_kernel<<<NNZq / 256, 256, 0, stream>>>(mask_batch, mask_node, cur, bucket);
    pool_kernel<<<(ROWS * 32) / 256, 256, 0, stream>>>(
        subnode_ids, mask_subnode, mask_values, emb_table, off, cnt, bucket, out);
}

// Round 3
// 207.856 us; speedup vs baseline: 8.8300x; 1.4598x over previous
//
#include <hip/hip_runtime.h>

#define Bq 16
#define Nq 2048
#define Sq 4096
#define Dq 128
#define NNZq 1048576
#define ROWS (Bq * Nq)   // 32768
#define CAP 64           // padded bucket capacity (mean fill = 32)
#define OVF_MAX 65536

// ---------- Phase 1: one-pass bucket fill ----------
// For each nonzero: resolve destination row + token, grab a slot in the row's
// padded bucket, store (token, value) contiguously. Overflow (pos>=CAP) goes
// to a fallback list handled with atomics after pool.
__global__ __launch_bounds__(256) void fill_kernel(
    const int* __restrict__ subnode_ids,   // [B,S]
    const int* __restrict__ mb,            // [NNZ]
    const int* __restrict__ mn,            // [NNZ]
    const int* __restrict__ ms,            // [NNZ]
    const float* __restrict__ mv,          // [NNZ]
    int* __restrict__ cnt,                 // [ROWS] (zeroed)
    int* __restrict__ bt,                  // [ROWS*CAP] tokens
    float* __restrict__ bv,                // [ROWS*CAP] values
    int* __restrict__ ovfn,                // overflow counter (zeroed)
    int* __restrict__ ovf)                 // overflow nz list
{
    int i = blockIdx.x * 256 + threadIdx.x;  // grid sized exactly to NNZ
    int b = mb[i];
    int row = b * Nq + mn[i];
    int tok = subnode_ids[b * Sq + ms[i]];
    float v = mv[i];
    int pos = atomicAdd(&cnt[row], 1);
    if (pos < CAP) {
        bt[row * CAP + pos] = tok;
        bv[row * CAP + pos] = v;
    } else {
        int o = atomicAdd(ovfn, 1);
        if (o < OVF_MAX) ovf[o] = i;
    }
}

// ---------- Phase 2: per-row gather + register accumulate + single store ----------
// 32 contiguous lanes own one output row; lane t owns float4 column t (512 B row).
__global__ __launch_bounds__(256) void pool_kernel(
    const float* __restrict__ emb,   // [VOCAB,D]
    const int* __restrict__ cnt,     // [ROWS]
    const int* __restrict__ bt,      // [ROWS*CAP]
    const float* __restrict__ bv,    // [ROWS*CAP]
    float* __restrict__ out)         // [ROWS,D]
{
    int gid  = blockIdx.x * 256 + threadIdx.x;
    int row  = gid >> 5;
    int lane = gid & 31;
    int n    = min(cnt[row], CAP);
    int base = row * CAP;

    float4 acc = {0.f, 0.f, 0.f, 0.f};
    for (int j0 = 0; j0 < n; j0 += 32) {
        int   myTok = 0;
        float myV   = 0.f;
        int j = j0 + lane;
        if (j < n) {             // coalesced 128 B metadata read per group
            myTok = bt[base + j];
            myV   = bv[base + j];
        }
        int lim = min(32, n - j0);
        for (int k = 0; k < lim; k++) {
            int   tok = __shfl(myTok, k, 32);
            float v   = __shfl(myV, k, 32);
            float4 e = reinterpret_cast<const float4*>(emb + (size_t)tok * Dq)[lane];
            acc.x += e.x * v;
            acc.y += e.y * v;
            acc.z += e.z * v;
            acc.w += e.w * v;
        }
    }
    reinterpret_cast<float4*>(out + (size_t)row * Dq)[lane] = acc;
}

// ---------- Phase 3: rare-overflow fallback (usually 0 entries) ----------
__global__ __launch_bounds__(256) void overflow_kernel(
    const int* __restrict__ subnode_ids,
    const int* __restrict__ mb, const int* __restrict__ mn,
    const int* __restrict__ ms, const float* __restrict__ mv,
    const float* __restrict__ emb,
    const int* __restrict__ ovfn, const int* __restrict__ ovf,
    float* __restrict__ out)
{
    int nov = min(*ovfn, OVF_MAX);
    for (int e = blockIdx.x * 256 + threadIdx.x; e < nov; e += gridDim.x * 256) {
        int i = ovf[e];
        int b = mb[i];
        int row = b * Nq + mn[i];
        int tok = subnode_ids[b * Sq + ms[i]];
        float v = mv[i];
        const float* src = emb + (size_t)tok * Dq;
        float* dst = out + (size_t)row * Dq;
        for (int d = 0; d < Dq; d++) unsafeAtomicAdd(dst + d, src[d] * v);
    }
}

extern "C" void kernel_launch(void* const* d_in, const int* in_sizes, int n_in,
                              void* d_out, int out_size, void* d_ws, size_t ws_size,
                              hipStream_t stream) {
    const int*   subnode_ids  = (const int*)d_in[0];
    const int*   mask_batch   = (const int*)d_in[1];
    const int*   mask_node    = (const int*)d_in[2];
    const int*   mask_subnode = (const int*)d_in[3];
    const float* mask_values  = (const float*)d_in[4];
    const float* emb_table    = (const float*)d_in[5];
    float*       out          = (float*)d_out;

    // ws layout (4-byte units): cnt[ROWS] | ovfn[1] | pad[63] | ovf[OVF_MAX] |
    //                           bt[ROWS*CAP] | bv[ROWS*CAP]   (~17.2 MB total)
    int*   cnt  = (int*)d_ws;
    int*   ovfn = cnt + ROWS;
    int*   ovf  = ovfn + 64;
    int*   bt   = ovf + OVF_MAX;
    float* bv   = (float*)(bt + ROWS * CAP);

    // Zero histogram + overflow counter (harness re-poisons ws each call).
    hipMemsetAsync(cnt, 0, (ROWS + 64) * sizeof(int), stream);

    fill_kernel<<<NNZq / 256, 256, 0, stream>>>(
        subnode_ids, mask_batch, mask_node, mask_subnode, mask_values,
        cnt, bt, bv, ovfn, ovf);
    pool_kernel<<<(ROWS * 32) / 256, 256, 0, stream>>>(
        emb_table, cnt, bt, bv, out);
    overflow_kernel<<<32, 256, 0, stream>>>(
        subnode_ids, mask_batch, mask_node, mask_subnode, mask_values,
        emb_table, ovfn, ovf, out);
}

// Round 5
// 204.005 us; speedup vs baseline: 8.9967x; 1.0189x over previous
//
#include <hip/hip_runtime.h>

#define Bq 16
#define Nq 2048
#define Sq 4096
#define Dq 128
#define NNZq 1048576
#define ROWS (Bq * Nq)   // 32768
#define CAP 64           // padded bucket capacity (mean fill = 32)
#define OVF_MAX 65536

typedef float vfloat4 __attribute__((ext_vector_type(4)));  // native vector, NT-store OK

// ---------- Phase 1: one-pass bucket fill ----------
// Packed (token, value) -> single scattered 8B nontemporal store per nonzero.
__global__ __launch_bounds__(256) void fill_kernel(
    const int* __restrict__ subnode_ids,   // [B,S]
    const int* __restrict__ mb,            // [NNZ]
    const int* __restrict__ mn,            // [NNZ]
    const int* __restrict__ ms,            // [NNZ]
    const float* __restrict__ mv,          // [NNZ]
    int* __restrict__ cnt,                 // [ROWS] (zeroed)
    long long* __restrict__ bp,            // [ROWS*CAP] packed (tok, value)
    int* __restrict__ ovfn,                // overflow counter (zeroed)
    int* __restrict__ ovf)                 // overflow nz list
{
    int i = blockIdx.x * 256 + threadIdx.x;  // grid sized exactly to NNZ
    int b = mb[i];
    int row = b * Nq + mn[i];
    int tok = subnode_ids[b * Sq + ms[i]];
    float v = mv[i];
    int pos = atomicAdd(&cnt[row], 1);
    if (pos < CAP) {
        long long pk = ((long long)__float_as_int(v) << 32) | (unsigned int)tok;
        __builtin_nontemporal_store(pk, bp + row * CAP + pos);
    } else {
        int o = atomicAdd(ovfn, 1);
        if (o < OVF_MAX) ovf[o] = i;
    }
}

// ---------- Phase 2: per-row gather + register accumulate + single store ----------
// 32 contiguous lanes own one output row; lane t owns float4 column t (512 B row).
__global__ __launch_bounds__(256) void pool_kernel(
    const float* __restrict__ emb,       // [VOCAB,D]
    const int* __restrict__ cnt,         // [ROWS]
    const long long* __restrict__ bp,    // [ROWS*CAP] packed (tok, value)
    float* __restrict__ out)             // [ROWS,D]
{
    int gid  = blockIdx.x * 256 + threadIdx.x;
    int row  = gid >> 5;
    int lane = gid & 31;
    int n    = min(cnt[row], CAP);
    int base = row * CAP;

    vfloat4 acc = {0.f, 0.f, 0.f, 0.f};
    for (int j0 = 0; j0 < n; j0 += 32) {
        long long pk = 0;
        int j = j0 + lane;
        if (j < n)   // coalesced 256 B nontemporal metadata read per group
            pk = __builtin_nontemporal_load(bp + base + j);
        int   myTok = (int)(unsigned int)(pk & 0xffffffffLL);
        float myV   = __int_as_float((int)(pk >> 32));

        int lim = min(32, n - j0);
        int k = 0;
        // Unroll by 4: 4 independent gathers in flight per acc chain step.
        for (; k + 4 <= lim; k += 4) {
            int   t0 = __shfl(myTok, k + 0, 32);
            int   t1 = __shfl(myTok, k + 1, 32);
            int   t2 = __shfl(myTok, k + 2, 32);
            int   t3 = __shfl(myTok, k + 3, 32);
            float v0 = __shfl(myV, k + 0, 32);
            float v1 = __shfl(myV, k + 1, 32);
            float v2 = __shfl(myV, k + 2, 32);
            float v3 = __shfl(myV, k + 3, 32);
            vfloat4 e0 = reinterpret_cast<const vfloat4*>(emb + (size_t)t0 * Dq)[lane];
            vfloat4 e1 = reinterpret_cast<const vfloat4*>(emb + (size_t)t1 * Dq)[lane];
            vfloat4 e2 = reinterpret_cast<const vfloat4*>(emb + (size_t)t2 * Dq)[lane];
            vfloat4 e3 = reinterpret_cast<const vfloat4*>(emb + (size_t)t3 * Dq)[lane];
            acc += e0 * v0;
            acc += e1 * v1;
            acc += e2 * v2;
            acc += e3 * v3;
        }
        for (; k < lim; k++) {
            int   tok = __shfl(myTok, k, 32);
            float v   = __shfl(myV, k, 32);
            vfloat4 e = reinterpret_cast<const vfloat4*>(emb + (size_t)tok * Dq)[lane];
            acc += e * v;
        }
    }
    __builtin_nontemporal_store(acc, reinterpret_cast<vfloat4*>(out + (size_t)row * Dq) + lane);
}

// ---------- Phase 3: rare-overflow fallback (usually 0 entries) ----------
__global__ __launch_bounds__(256) void overflow_kernel(
    const int* __restrict__ subnode_ids,
    const int* __restrict__ mb, const int* __restrict__ mn,
    const int* __restrict__ ms, const float* __restrict__ mv,
    const float* __restrict__ emb,
    const int* __restrict__ ovfn, const int* __restrict__ ovf,
    float* __restrict__ out)
{
    int nov = min(*ovfn, OVF_MAX);
    for (int e = blockIdx.x * 256 + threadIdx.x; e < nov; e += gridDim.x * 256) {
        int i = ovf[e];
        int b = mb[i];
        int row = b * Nq + mn[i];
        int tok = subnode_ids[b * Sq + ms[i]];
        float v = mv[i];
        const float* src = emb + (size_t)tok * Dq;
        float* dst = out + (size_t)row * Dq;
        for (int d = 0; d < Dq; d++) unsafeAtomicAdd(dst + d, src[d] * v);
    }
}

extern "C" void kernel_launch(void* const* d_in, const int* in_sizes, int n_in,
                              void* d_out, int out_size, void* d_ws, size_t ws_size,
                              hipStream_t stream) {
    const int*   subnode_ids  = (const int*)d_in[0];
    const int*   mask_batch   = (const int*)d_in[1];
    const int*   mask_node    = (const int*)d_in[2];
    const int*   mask_subnode = (const int*)d_in[3];
    const float* mask_values  = (const float*)d_in[4];
    const float* emb_table    = (const float*)d_in[5];
    float*       out          = (float*)d_out;

    // ws layout (4-byte units): cnt[ROWS] | ovfn[1] pad[63] | ovf[OVF_MAX] | bp[ROWS*CAP] (8B each)
    int*       cnt  = (int*)d_ws;
    int*       ovfn = cnt + ROWS;
    int*       ovf  = ovfn + 64;
    long long* bp   = (long long*)(ovf + OVF_MAX);

    // Zero histogram + overflow counter (harness re-poisons ws each call).
    (void)hipMemsetAsync(cnt, 0, (ROWS + 64) * sizeof(int), stream);

    fill_kernel<<<NNZq / 256, 256, 0, stream>>>(
        subnode_ids, mask_batch, mask_node, mask_subnode, mask_values,
        cnt, bp, ovfn, ovf);
    pool_kernel<<<(ROWS * 32) / 256, 256, 0, stream>>>(
        emb_table, cnt, bp, out);
    overflow_kernel<<<32, 256, 0, stream>>>(
        subnode_ids, mask_batch, mask_node, mask_subnode, mask_values,
        emb_table, ovfn, ovf, out);
}

// Round 6
// 200.676 us; speedup vs baseline: 9.1459x; 1.0166x over previous
//
#include <hip/hip_runtime.h>

#define Bq 16
#define Nq 2048
#define Sq 4096
#define Dq 128
#define NNZq 1048576
#define ROWS (Bq * Nq)   // 32768
#define CAP 64           // padded bucket capacity (mean fill = 32)
#define OVF_MAX 65536
#define FB 4             // fill: entries per thread (independent atomic chains)

typedef float vfloat4 __attribute__((ext_vector_type(4)));  // native vector, NT-store OK

// ---------- Phase 1: one-pass bucket fill, batched x4 for MLP ----------
__global__ __launch_bounds__(256) void fill_kernel(
    const int* __restrict__ subnode_ids,   // [B,S]
    const int* __restrict__ mb,            // [NNZ]
    const int* __restrict__ mn,            // [NNZ]
    const int* __restrict__ ms,            // [NNZ]
    const float* __restrict__ mv,          // [NNZ]
    int* __restrict__ cnt,                 // [ROWS] (zeroed)
    long long* __restrict__ bp,            // [ROWS*CAP] packed (tok, value)
    int* __restrict__ ovfn,                // overflow counter (zeroed)
    int* __restrict__ ovf)                 // overflow nz list
{
    int base = blockIdx.x * (256 * FB) + threadIdx.x;  // block owns contiguous 1024

    int   row[FB], tok[FB], pos[FB];
    float v[FB];
    #pragma unroll
    for (int k = 0; k < FB; k++) {                 // coalesced index loads + token gather
        int i  = base + k * 256;
        int b  = mb[i];
        row[k] = b * Nq + mn[i];
        tok[k] = subnode_ids[b * Sq + ms[i]];
        v[k]   = mv[i];
    }
    #pragma unroll
    for (int k = 0; k < FB; k++)                   // 4 independent return-atomics in flight
        pos[k] = atomicAdd(&cnt[row[k]], 1);
    #pragma unroll
    for (int k = 0; k < FB; k++) {
        if (pos[k] < CAP) {
            long long pk = ((long long)__float_as_int(v[k]) << 32) | (unsigned int)tok[k];
            __builtin_nontemporal_store(pk, bp + row[k] * CAP + pos[k]);
        } else {
            int o = atomicAdd(ovfn, 1);
            if (o < OVF_MAX) ovf[o] = base + k * 256;
        }
    }
}

// ---------- Phase 2: per-row gather + register accumulate + single store ----------
// 32 contiguous lanes own one output row; lane t owns float4 column t (512 B row).
__global__ __launch_bounds__(256) void pool_kernel(
    const float* __restrict__ emb,       // [VOCAB,D]
    const int* __restrict__ cnt,         // [ROWS]
    const long long* __restrict__ bp,    // [ROWS*CAP] packed (tok, value)
    float* __restrict__ out)             // [ROWS,D]
{
    int gid  = blockIdx.x * 256 + threadIdx.x;
    int row  = gid >> 5;
    int lane = gid & 31;
    int n    = min(cnt[row], CAP);
    int base = row * CAP;

    vfloat4 acc = {0.f, 0.f, 0.f, 0.f};
    for (int j0 = 0; j0 < n; j0 += 32) {
        long long pk = 0;
        int j = j0 + lane;
        if (j < n)   // coalesced 256 B nontemporal metadata read per group
            pk = __builtin_nontemporal_load(bp + base + j);
        int   myTok = (int)(unsigned int)(pk & 0xffffffffLL);
        float myV   = __int_as_float((int)(pk >> 32));

        int lim = min(32, n - j0);
        int k = 0;
        // Unroll by 8: 8 independent 512B row-gathers in flight per group.
        for (; k + 8 <= lim; k += 8) {
            int   tk[8];
            float vk[8];
            #pragma unroll
            for (int u = 0; u < 8; u++) {
                tk[u] = __shfl(myTok, k + u, 32);
                vk[u] = __shfl(myV,   k + u, 32);
            }
            vfloat4 e[8];
            #pragma unroll
            for (int u = 0; u < 8; u++)
                e[u] = reinterpret_cast<const vfloat4*>(emb + (size_t)tk[u] * Dq)[lane];
            #pragma unroll
            for (int u = 0; u < 8; u++)
                acc += e[u] * vk[u];
        }
        for (; k < lim; k++) {
            int   tok = __shfl(myTok, k, 32);
            float v   = __shfl(myV, k, 32);
            vfloat4 e = reinterpret_cast<const vfloat4*>(emb + (size_t)tok * Dq)[lane];
            acc += e * v;
        }
    }
    __builtin_nontemporal_store(acc, reinterpret_cast<vfloat4*>(out + (size_t)row * Dq) + lane);
}

// ---------- Phase 3: rare-overflow fallback (usually 0 entries) ----------
__global__ __launch_bounds__(256) void overflow_kernel(
    const int* __restrict__ subnode_ids,
    const int* __restrict__ mb, const int* __restrict__ mn,
    const int* __restrict__ ms, const float* __restrict__ mv,
    const float* __restrict__ emb,
    const int* __restrict__ ovfn, const int* __restrict__ ovf,
    float* __restrict__ out)
{
    int nov = min(*ovfn, OVF_MAX);
    for (int e = blockIdx.x * 256 + threadIdx.x; e < nov; e += gridDim.x * 256) {
        int i = ovf[e];
        int b = mb[i];
        int row = b * Nq + mn[i];
        int tok = subnode_ids[b * Sq + ms[i]];
        float v = mv[i];
        const float* src = emb + (size_t)tok * Dq;
        float* dst = out + (size_t)row * Dq;
        for (int d = 0; d < Dq; d++) unsafeAtomicAdd(dst + d, src[d] * v);
    }
}

extern "C" void kernel_launch(void* const* d_in, const int* in_sizes, int n_in,
                              void* d_out, int out_size, void* d_ws, size_t ws_size,
                              hipStream_t stream) {
    const int*   subnode_ids  = (const int*)d_in[0];
    const int*   mask_batch   = (const int*)d_in[1];
    const int*   mask_node    = (const int*)d_in[2];
    const int*   mask_subnode = (const int*)d_in[3];
    const float* mask_values  = (const float*)d_in[4];
    const float* emb_table    = (const float*)d_in[5];
    float*       out          = (float*)d_out;

    // ws layout (4-byte units): cnt[ROWS] | ovfn[1] pad[63] | ovf[OVF_MAX] | bp[ROWS*CAP] (8B each)
    int*       cnt  = (int*)d_ws;
    int*       ovfn = cnt + ROWS;
    int*       ovf  = ovfn + 64;
    long long* bp   = (long long*)(ovf + OVF_MAX);

    // Zero histogram + overflow counter (harness re-poisons ws each call).
    (void)hipMemsetAsync(cnt, 0, (ROWS + 64) * sizeof(int), stream);

    fill_kernel<<<NNZq / (256 * FB), 256, 0, stream>>>(
        subnode_ids, mask_batch, mask_node, mask_subnode, mask_values,
        cnt, bp, ovfn, ovf);
    pool_kernel<<<(ROWS * 32) / 256, 256, 0, stream>>>(
        emb_table, cnt, bp, out);
    overflow_kernel<<<32, 256, 0, stream>>>(
        subnode_ids, mask_batch, mask_node, mask_subnode, mask_values,
        emb_table, ovfn, ovf, out);
}